// Round 6
// baseline (18.170 us; speedup 1.0000x reference)
//
#include <hip/hip_runtime.h>

#define RPB 64              // residues per block (one per lane, 4 specialized waves)
#define FRS 18              // LDS floats per frame (16 + 2 pad) -> bank spread, 8B aligned
#define RSS (9*FRS)         // 162 floats per residue

typedef float __attribute__((ext_vector_type(4))) fvec4;   // clang-native for NT stores

// ---------- helpers ----------

__device__ __forceinline__ float rsqz(float d) { return rsqrtf(fmaxf(d, 1e-24f)); }

__device__ __forceinline__ void angNorm(float x, float y, float& c, float& s) {
    float inv = rsqz(x*x + y*y);
    c = x * inv; s = y * inv;
}

__device__ __forceinline__ void loadMat4(const float* __restrict__ p, float B[4][4]) {
    const float4* q4 = reinterpret_cast<const float4*>(p);
#pragma unroll
    for (int i = 0; i < 4; ++i) {
        float4 r = q4[i];
        B[i][0]=r.x; B[i][1]=r.y; B[i][2]=r.z; B[i][3]=r.w;
    }
}

__device__ __forceinline__ void storeRowLDS(float* dst, float a, float b, float c, float d) {
    *reinterpret_cast<float2*>(dst)     = make_float2(a, b);
    *reinterpret_cast<float2*>(dst + 2) = make_float2(c, d);
}

__device__ __forceinline__ void storeMatLDS(float* dst, const float M[4][4]) {
#pragma unroll
    for (int i = 0; i < 4; ++i)
        storeRowLDS(dst + i*4, M[i][0], M[i][1], M[i][2], M[i][3]);
}

__device__ __forceinline__ void storeAffineLDS(float* dst, const float f[3][4]) {
#pragma unroll
    for (int i = 0; i < 3; ++i)
        storeRowLDS(dst + i*4, f[i][0], f[i][1], f[i][2], f[i][3]);
    storeRowLDS(dst + 12, 0.f, 0.f, 0.f, 1.f);
}

// C = A * B, A affine as 3 rows of 4 (row3 implicitly [0,0,0,1]); C row3 = B row3
__device__ __forceinline__ void affineMul(const float a[3][4], const float B[4][4], float C[4][4]) {
#pragma unroll
    for (int i = 0; i < 3; ++i)
#pragma unroll
        for (int j = 0; j < 4; ++j)
            C[i][j] = a[i][0]*B[0][j] + a[i][1]*B[1][j] + a[i][2]*B[2][j] + a[i][3]*B[3][j];
#pragma unroll
    for (int j = 0; j < 4; ++j) C[3][j] = B[3][j];
}

__device__ __forceinline__ void mat4Mul(const float A[4][4], const float B[4][4], float C[4][4]) {
#pragma unroll
    for (int i = 0; i < 4; ++i)
#pragma unroll
        for (int j = 0; j < 4; ++j)
            C[i][j] = A[i][0]*B[0][j] + A[i][1]*B[1][j] + A[i][2]*B[2][j] + A[i][3]*B[3][j];
}

// M = M @ rotX(c,s): only columns 1,2 change
__device__ __forceinline__ void postRotX(float M[4][4], float c, float s) {
#pragma unroll
    for (int i = 0; i < 4; ++i) {
        float m1 = M[i][1], m2 = M[i][2];
        M[i][1] = c*m1 + s*m2;
        M[i][2] = c*m2 - s*m1;
    }
}

__device__ __forceinline__ void rotAxis3(float G[3][3], float c, float s,
                                         float u0, float u1, float u2) {
    float omc = 1.0f - c;
    G[0][0] = c + u0*u0*omc;    G[0][1] = u0*u1*omc - u2*s; G[0][2] = u0*u2*omc + u1*s;
    G[1][0] = u0*u1*omc + u2*s; G[1][1] = c + u1*u1*omc;    G[1][2] = u1*u2*omc - u0*s;
    G[2][0] = u0*u2*omc - u1*s; G[2][1] = u1*u2*omc + u0*s; G[2][2] = c + u2*u2*omc;
}

__device__ __forceinline__ void mat3Mul(const float A[3][3], const float B[3][3], float C[3][3]) {
#pragma unroll
    for (int i = 0; i < 3; ++i)
#pragma unroll
        for (int j = 0; j < 3; ++j)
            C[i][j] = A[i][0]*B[0][j] + A[i][1]*B[1][j] + A[i][2]*B[2][j];
}

// rigid_from_3_points -> affine rows {R | T}, R columns are e1,e2,e3
__device__ __forceinline__ void computeF0(const float* __restrict__ xyz, int t, float f0[3][4]) {
    const float* p = xyz + (size_t)t * 9;
    float N0=p[0], N1=p[1], N2=p[2];
    float A0=p[3], A1=p[4], A2=p[5];
    float C0=p[6], C1=p[7], C2=p[8];

    float v10=C0-A0, v11=C1-A1, v12=C2-A2;
    float v20=N0-A0, v21=N1-A1, v22=N2-A2;
    float i1 = rsqz(v10*v10 + v11*v11 + v12*v12);
    float e10=v10*i1, e11=v11*i1, e12=v12*i1;
    float d  = e10*v20 + e11*v21 + e12*v22;
    float u20=v20-e10*d, u21=v21-e11*d, u22=v22-e12*d;
    float i2 = rsqz(u20*u20 + u21*u21 + u22*u22);
    float e20=u20*i2, e21=u21*i2, e22=u22*i2;
    float e30=e11*e22 - e12*e21;
    float e31=e12*e20 - e10*e22;
    float e32=e10*e21 - e11*e20;

    f0[0][0]=e10; f0[0][1]=e20; f0[0][2]=e30; f0[0][3]=A0;
    f0[1][0]=e11; f0[1][1]=e21; f0[1][2]=e31; f0[1][3]=A1;
    f0[2][0]=e12; f0[2][1]=e22; f0[2][2]=e32; f0[2][3]=A2;
}

// ---------------------------- fused kernel ----------------------------
// 256 threads = 4 waves, 64 residues/block. Wave specialization:
//  wv0: F0, F1     wv1: F2, F3     wv2: axes + F8 -> LDS
//  wv3: P4..P7 suffix chain (registers); after barrier reads F8, emits F4..F7
// barrier; all: coalesced NT frame stores + row-parallel atom transforms.

__global__ __launch_bounds__(256, 3) void fused_kernel(
    const int*   __restrict__ seq,     // (BL)
    const float* __restrict__ xyz,     // (BL,3,3)
    const float* __restrict__ alphas,  // (BL,10,2)
    const int*   __restrict__ bidx,    // (NAA,36)
    const float* __restrict__ RTs,     // (NAA,7,4,4)
    const float* __restrict__ xibf,    // (NAA,36,4)
    float*       __restrict__ out_fr,  // (BL,9,4,4)
    float*       __restrict__ out_xyz, // (BL,36,3)
    int BL)
{
    __shared__ float lds_fr[RPB * RSS];
    __shared__ int   lds_seq[RPB];

    const int tid  = threadIdx.x;
    const int wv   = tid >> 6;
    const int r    = tid & 63;
    const int base = blockIdx.x * RPB;
    const int t    = base + r;
    const bool valid = (t < BL);

    int s = 0;
    if (valid) s = seq[t];
    const float* rb = RTs + (size_t)s * 112;
    const float* al = alphas + (size_t)t * 20;
    float* fl = lds_fr + r * RSS;

    // registers carried across barrier 1 (wave 3)
    float P4[4][4], P5[4][4], P6[4][4], P7[4][4];

    if (valid) {
        if (wv == 0) {
            lds_seq[r] = s;
            float f0[3][4]; computeF0(xyz, t, f0);
            storeAffineLDS(fl, f0);

            float2 a0 = *reinterpret_cast<const float2*>(al + 0);
            float c0, s0; angNorm(a0.x, a0.y, c0, s0);
            float B[4][4], F[4][4];
            loadMat4(rb + 0, B);
            affineMul(f0, B, F); postRotX(F, c0, s0);
            storeMatLDS(fl + 1*FRS, F);
        } else if (wv == 1) {
            float f0[3][4]; computeF0(xyz, t, f0);
            float2 a1 = *reinterpret_cast<const float2*>(al + 2);
            float2 a2 = *reinterpret_cast<const float2*>(al + 4);
            float c, sn;
            float B[4][4], F[4][4];
            angNorm(a1.x, a1.y, c, sn);
            loadMat4(rb + 16, B); affineMul(f0, B, F); postRotX(F, c, sn);
            storeMatLDS(fl + 2*FRS, F);
            angNorm(a2.x, a2.y, c, sn);
            loadMat4(rb + 32, B); affineMul(f0, B, F); postRotX(F, c, sn);
            storeMatLDS(fl + 3*FRS, F);
        } else if (wv == 2) {
            float f0[3][4]; computeF0(xyz, t, f0);
            // CB rotation axes from base geometry
            const float* bxp = xibf + (size_t)s * 144;
            float4 b0 = reinterpret_cast<const float4*>(bxp)[0];
            float4 b1 = reinterpret_cast<const float4*>(bxp)[1];
            float4 b2 = reinterpret_cast<const float4*>(bxp)[2];
            float4 b4 = reinterpret_cast<const float4*>(bxp)[4];

            float NCr0 = 0.5f*(b2.x + b0.x), NCr1 = 0.5f*(b2.y + b0.y), NCr2 = 0.5f*(b2.z + b0.z);
            float ba0 = b4.x - b1.x, ba1 = b4.y - b1.y, ba2 = b4.z - b1.z;
            float w0 = NCr0 - b1.x, w1 = NCr1 - b1.y, w2 = NCr2 - b1.z;
            float x10 = ba1*w2 - ba2*w1, x11 = ba2*w0 - ba0*w2, x12 = ba0*w1 - ba1*w0;
            float in1 = rsqz(x10*x10 + x11*x11 + x12*x12);
            x10 *= in1; x11 *= in1; x12 *= in1;
            float NCp0 = b2.x - b0.x, NCp1 = b2.y - b0.y, NCp2 = b2.z - b0.z;
            float dp = NCp0*NCr0 + NCp1*NCr1 + NCp2*NCr2;
            float dr = NCr0*NCr0 + NCr1*NCr1 + NCr2*NCr2;
            float sf = dp / dr;
            float q0 = NCp0 - sf*NCr0, q1 = NCp1 - sf*NCr1, q2 = NCp2 - sf*NCr2;
            float x20 = ba1*q2 - ba2*q1, x21 = ba2*q0 - ba0*q2, x22 = ba0*q1 - ba1*q0;
            float in2 = rsqz(x20*x20 + x21*x21 + x22*x22);
            x20 *= in2; x21 *= in2; x22 *= in2;

            float2 a7 = *reinterpret_cast<const float2*>(al + 14);
            float2 a8 = *reinterpret_cast<const float2*>(al + 16);
            float c7, s7, c8, s8;
            angNorm(a7.x, a7.y, c7, s7);
            angNorm(a8.x, a8.y, c8, s8);
            float G1[3][3], G2[3][3], G12[3][3], R8[3][3];
            rotAxis3(G1, c7, s7, x10, x11, x12);
            rotAxis3(G2, c8, s8, x20, x21, x22);
            mat3Mul(G1, G2, G12);
            float R0[3][3] = { {f0[0][0],f0[0][1],f0[0][2]},
                               {f0[1][0],f0[1][1],f0[1][2]},
                               {f0[2][0],f0[2][1],f0[2][2]} };
            mat3Mul(R0, G12, R8);
            float f8[3][4];
#pragma unroll
            for (int i = 0; i < 3; ++i) {
                f8[i][0] = R8[i][0]; f8[i][1] = R8[i][1]; f8[i][2] = R8[i][2];
                f8[i][3] = f0[i][3];
            }
            storeAffineLDS(fl + 8*FRS, f8);
        } else {
            // wv == 3: suffix chain in base coordinates, kept in registers
            float2 a3 = *reinterpret_cast<const float2*>(al + 6);
            float2 a4 = *reinterpret_cast<const float2*>(al + 8);
            float2 a5 = *reinterpret_cast<const float2*>(al + 10);
            float2 a6 = *reinterpret_cast<const float2*>(al + 12);
            float2 a9 = *reinterpret_cast<const float2*>(al + 18);
            float c3,s3, c4,s4, c5,s5, c6,s6, c9,s9;
            angNorm(a3.x, a3.y, c3, s3);
            angNorm(a4.x, a4.y, c4, s4);
            angNorm(a5.x, a5.y, c5, s5);
            angNorm(a6.x, a6.y, c6, s6);
            angNorm(a9.x, a9.y, c9, s9);

            // M = rotX(c3,s3) @ rotZ(c9,s9), 3x3
            float M00 = c9,    M01 = -s9;
            float M10 = c3*s9, M11 = c3*c9, M12 = -s3;
            float M20 = s3*s9, M21 = s3*c9, M22 = c3;

            float B[4][4];
            loadMat4(rb + 48, B);
#pragma unroll
            for (int i = 0; i < 4; ++i) {
                P4[i][0] = B[i][0]*M00 + B[i][1]*M10 + B[i][2]*M20;
                P4[i][1] = B[i][0]*M01 + B[i][1]*M11 + B[i][2]*M21;
                P4[i][2] =               B[i][1]*M12 + B[i][2]*M22;
                P4[i][3] = B[i][3];
            }
            loadMat4(rb + 64, B); mat4Mul(P4, B, P5); postRotX(P5, c4, s4);
            loadMat4(rb + 80, B); mat4Mul(P5, B, P6); postRotX(P6, c5, s5);
            loadMat4(rb + 96, B); mat4Mul(P6, B, P7); postRotX(P7, c6, s6);
        }
    }
    __syncthreads();

    if (valid && wv == 3) {
        // read F8 rotation+translation written by wave 2
        float f8b[3][4];
        const float* qp = fl + 8*FRS;
#pragma unroll
        for (int i = 0; i < 3; ++i) {
            float2 u = *reinterpret_cast<const float2*>(qp + i*4);
            float2 w = *reinterpret_cast<const float2*>(qp + i*4 + 2);
            f8b[i][0]=u.x; f8b[i][1]=u.y; f8b[i][2]=w.x; f8b[i][3]=w.y;
        }
        float F[4][4];
        affineMul(f8b, P4, F); storeMatLDS(fl + 4*FRS, F);
        affineMul(f8b, P5, F); storeMatLDS(fl + 5*FRS, F);
        affineMul(f8b, P6, F); storeMatLDS(fl + 6*FRS, F);
        affineMul(f8b, P7, F); storeMatLDS(fl + 7*FRS, F);
    }
    __syncthreads();

    // phase 2a: frames LDS -> global, dense NT float4 stores (RPB*36 = 2304 = 9*256)
#pragma unroll
    for (int k = 0; k < 9; ++k) {
        int c = tid + k*256;
        int res = c / 36;
        int q = c - res*36;            // q = frame*4 + row
        int tt = base + res;
        if (tt < BL) {
            const float* p = lds_fr + res*RSS + (q >> 2)*FRS + (q & 3)*4;
            float2 u = *reinterpret_cast<const float2*>(p);
            float2 w = *reinterpret_cast<const float2*>(p + 2);
            fvec4 v4 = { u.x, u.y, w.x, w.y };
            __builtin_nontemporal_store(v4,
                reinterpret_cast<fvec4*>(out_fr) + (size_t)tt*36 + q);
        }
    }

    // phase 2b: row-parallel atom transforms, dense NT dword stores
    // RPB*36*3 = 6912 = 27*256 ; flat out index = base*108 + c
#pragma unroll
    for (int k = 0; k < 27; ++k) {
        int c = tid + k*256;
        int res = c / 108;
        int rem = c - res*108;
        int a   = rem / 3;
        int row = rem - a*3;
        int tt = base + res;
        if (tt < BL) {
            int ss  = lds_seq[res];
            int idx = bidx[ss*36 + a];
            const float* fp = lds_fr + res*RSS + idx*FRS + row*4;
            float2 u = *reinterpret_cast<const float2*>(fp);
            float2 w = *reinterpret_cast<const float2*>(fp + 2);
            float4 v = *reinterpret_cast<const float4*>(xibf + ((size_t)ss*36 + a)*4);
            float val = u.x*v.x + u.y*v.y + w.x*v.z + w.y*v.w;
            __builtin_nontemporal_store(val, out_xyz + (size_t)base*108 + c);
        }
    }
}

// ---------------------------- launch ----------------------------

extern "C" void kernel_launch(void* const* d_in, const int* in_sizes, int n_in,
                              void* d_out, int out_size, void* d_ws, size_t ws_size,
                              hipStream_t stream) {
    const int*   seq    = (const int*)  d_in[0];
    const float* xyz    = (const float*)d_in[1];
    const float* alphas = (const float*)d_in[2];
    const int*   bidx   = (const int*)  d_in[3];
    const float* RTs    = (const float*)d_in[4];
    const float* xibf   = (const float*)d_in[5];
    float*       out    = (float*)d_out;

    int BL = in_sizes[0];                       // B * L
    float* out_xyz = out + (size_t)BL * 144;

    int blocks = (BL + RPB - 1) / RPB;
    fused_kernel<<<blocks, 256, 0, stream>>>(seq, xyz, alphas, bidx, RTs, xibf,
                                             out, out_xyz, BL);
}